// Round 5
// baseline (94.662 us; speedup 1.0000x reference)
//
#include <hip/hip_runtime.h>

// out[n,m] = exp(-0.5 * sum_d (x[n,d]-c[m,d])^2 / s2[m,d]) / sqrt((2pi)^D * prod s2)
// Fast path (d-uniform variance per center; true for bench sigma==1):
//   out = exp2( L2E*(x.A) + qc*r2[n] + c0 ),  A = c/s2,  qc = -0.5*L2E/s2,
//   c0 = -0.5*L2E*(c.A) - 0.5*(D*log2(2pi) + sum log2 s2),  r2[n] = sum x^2
//
// Round-5 structure:
//  * x row broadcast via LDS (lgkmcnt) so out-stores (vmcnt) never enter the
//    dependency chain -- rounds 2-4 serialized ~600 cyc/iter on vmcnt(0).
//  * MPT=2: each thread owns m and m+256; 8 ds_read_b128/row serve 2 outputs.
//  * centers/sigma prologue transposed through wave-private LDS scratch
//    (coalesced global reads; stride-33 rows -> conflict-free readback).

#define N_   16384
#define M_   1024
#define D_   32
#define NT   64
#define BLK  256
#define MW   (BLK / 64)
#define SSTR 33

typedef float v4f __attribute__((ext_vector_type(4)));

__global__ __launch_bounds__(BLK, 2) void rbf_kernel(
    const float* __restrict__ x, const float* __restrict__ centers,
    const float* __restrict__ sigma, float* __restrict__ out)
{
    const int tid  = threadIdx.x;
    const int lane = tid & 63;
    const int wv   = tid >> 6;
    const int n0   = blockIdx.y * NT;
    const int mbA  = blockIdx.x * (BLK * 2) + wv * 64;   // this wave's first m, set A
    const int mbB  = mbA + BLK;                          // set B (= +256)

    __shared__ float xs[NT * D_];          // 8 KB x tile
    __shared__ float r2s[NT];              // per-row sum x^2
    __shared__ float scr[MW][64 * SSTR];   // wave-private transpose scratch

    // ---- stage x tile (coalesced) + r2 via 8-lane shuffle reduction ----
    {
        const float4* xg  = (const float4*)(x + (size_t)n0 * D_);
        float4*       xs4 = (float4*)xs;
        #pragma unroll
        for (int j = 0; j < (NT * D_ / 4) / BLK; ++j) {
            int f = j * BLK + tid;                 // float4 index; 8 per row
            float4 v = xg[f];
            xs4[f] = v;
            float s = fmaf(v.x, v.x, fmaf(v.y, v.y, fmaf(v.z, v.z, v.w * v.w)));
            s += __shfl_xor(s, 1);
            s += __shfl_xor(s, 2);
            s += __shfl_xor(s, 4);
            if ((tid & 7) == 0) r2s[f >> 3] = s;
        }
    }
    __syncthreads();   // only barrier; everything after is wave-local

    float* sw = scr[wv];

    // coalesced global -> wave-private LDS chunk (64 m x 32 d, row stride 33)
    auto stagechunk = [&](const float* P, int mbase) {
        const float4* P4 = (const float4*)(P + (size_t)mbase * D_);
        #pragma unroll
        for (int k = 0; k < 8; ++k) {
            int f = k * 64 + lane;
            float4 v = P4[f];                       // 16 B/lane coalesced
            int off = (f >> 3) * SSTR + (f & 7) * 4;
            sw[off + 0] = v.x; sw[off + 1] = v.y;
            sw[off + 2] = v.z; sw[off + 3] = v.w;
        }
    };

    auto sigscan = [&](int mbase, float& s2_0, float& ld) -> bool {
        stagechunk(sigma, mbase);
        const float* row = sw + lane * SSTR;        // bank (lane+d)%32: conflict-free
        float s0 = row[0];
        s2_0 = s0 * s0;
        bool uf = true; ld = 0.f;
        #pragma unroll
        for (int d = 0; d < D_; ++d) {
            float s  = row[d];
            float s2 = s * s;
            uf = uf && (s2 == s2_0);
            ld += log2f(s2);                        // exactly 0 for sigma==1
        }
        return uf;
    };

    auto cscan = [&](int mbase, float w0, v4f* A) -> float {
        stagechunk(centers, mbase);
        const float* row = sw + lane * SSTR;
        float b = 0.f;
        #pragma unroll
        for (int k = 0; k < 8; ++k) {
            v4f c = { row[4*k], row[4*k+1], row[4*k+2], row[4*k+3] };
            v4f a = c * w0;
            A[k] = a;
            b = fmaf(c.x, a.x, fmaf(c.y, a.y, fmaf(c.z, a.z, fmaf(c.w, a.w, b))));
        }
        return b;
    };

    float s2A, ldA, s2B, ldB;
    v4f A0[8], A1[8];
    bool ufA = sigscan(mbA, s2A, ldA);
    const float w0A = 1.0f / s2A;
    float bA = cscan(mbA, w0A, A0);
    bool ufB = sigscan(mbB, s2B, ldB);
    const float w0B = 1.0f / s2B;
    float bB = cscan(mbB, w0B, A1);

    const float L2E      = 1.4426950408889634f;
    const float LOG2_2PI = 2.6514961294723187f;

    if (__all((int)(ufA && ufB))) {
        // keep A register-resident: compiler must not re-sink the ds_reads
        #pragma unroll
        for (int k = 0; k < 8; ++k) {
            asm volatile("" : "+v"(A0[k]));
            asm volatile("" : "+v"(A1[k]));
        }
        const float c0A = fmaf(-0.5f * L2E, bA, -0.5f * (D_ * LOG2_2PI + ldA));
        const float c0B = fmaf(-0.5f * L2E, bB, -0.5f * (D_ * LOG2_2PI + ldB));
        const float qcA = -0.5f * L2E * w0A;
        const float qcB = -0.5f * L2E * w0B;

        float* oA = out + (size_t)n0 * M_ + mbA + lane;
        float* oB = oA + BLK;
        #pragma unroll 1
        for (int i = 0; i < NT; ++i) {
            const v4f* xr = (const v4f*)(xs + i * D_);   // wave-uniform: broadcast
            v4f pa = {0,0,0,0}, pb = {0,0,0,0};
            v4f qa = {0,0,0,0}, qb = {0,0,0,0};
            #pragma unroll
            for (int k = 0; k < 8; k += 2) {
                v4f x0 = xr[k], x1 = xr[k + 1];          // ds_read_b128
                pa += x0 * A0[k];     pb += x1 * A0[k + 1];
                qa += x0 * A1[k];     qb += x1 * A1[k + 1];
            }
            v4f ps = pa + pb, qs = qa + qb;
            float SA = (ps.x + ps.y) + (ps.z + ps.w);
            float SB = (qs.x + qs.y) + (qs.z + qs.w);
            float r2 = r2s[i];
            float fA = fmaf(L2E, SA, fmaf(qcA, r2, c0A));
            float fB = fmaf(L2E, SB, fmaf(qcB, r2, c0B));
            __builtin_nontemporal_store(__builtin_amdgcn_exp2f(fA), oA + (size_t)i * M_);
            __builtin_nontemporal_store(__builtin_amdgcn_exp2f(fB), oB + (size_t)i * M_);
        }
    } else {
        // general path: arbitrary per-d sigma, correct, not perf-tuned
        #pragma unroll 1
        for (int half = 0; half < 2; ++half) {
            const int m = (half ? mbB : mbA) + lane;
            const float* cg = centers + (size_t)m * D_;
            const float* sg = sigma   + (size_t)m * D_;
            const float ld  = half ? ldB : ldA;
            const float c0  = -0.5f * (D_ * LOG2_2PI + ld);
            #pragma unroll 1
            for (int i = 0; i < NT; ++i) {
                const float* xr = xs + i * D_;
                float a0 = 0.f, a1 = 0.f;
                #pragma unroll
                for (int d = 0; d < D_; d += 2) {
                    float s0 = sg[d], s1 = sg[d + 1];
                    float t0 = xr[d]     - cg[d];
                    float t1 = xr[d + 1] - cg[d + 1];
                    a0 = fmaf(t0 * (1.0f / (s0 * s0)), t0, a0);
                    a1 = fmaf(t1 * (1.0f / (s1 * s1)), t1, a1);
                }
                float f = fmaf(-0.5f * L2E, a0 + a1, c0);
                out[(size_t)(n0 + i) * M_ + m] = __builtin_amdgcn_exp2f(f);
            }
        }
    }
}

extern "C" void kernel_launch(void* const* d_in, const int* in_sizes, int n_in,
                              void* d_out, int out_size, void* d_ws, size_t ws_size,
                              hipStream_t stream) {
    const float* x = (const float*)d_in[0];
    const float* c = (const float*)d_in[1];
    const float* s = (const float*)d_in[2];
    float* out = (float*)d_out;
    dim3 grid(M_ / (BLK * 2), N_ / NT);
    rbf_kernel<<<grid, BLK, 0, stream>>>(x, c, s, out);
}